// Round 8
// baseline (315.849 us; speedup 1.0000x reference)
//
#include <hip/hip_runtime.h>
#include <hip/hip_bf16.h>

typedef __hip_bfloat16 bf16;
typedef short bf16x8 __attribute__((ext_vector_type(8)));
typedef float f32x4 __attribute__((ext_vector_type(4)));
typedef float f32x2 __attribute__((ext_vector_type(2)));

#define N_NODES  10000
#define G_GRAPHS 200
#define EL_EDGES 160000
#define EG_EDGES 500000
#define S_DIM    256
#define APAD     264   // LDS row stride in bf16 (528 B: 16B-aligned, bank-benign)

// ---------------- workspace layout (float offsets) ----------------
#define WS_FLAG   0         // input dtype flag (0=bf16, 1=f32)
#define WS_SUMS   16        // 800 (sumx,sumy,sumz,count per graph)
#define WS_POSC   1024      // 30000: raw f32 pos, then centered in-place
#define WS_WD     31232     // 256  W_b0 row 256, PERMUTED to storage order
#define WS_BB0    31488     // 256  b_b0, PERMUTED to storage order
#define WS_WB1    31744     // 2560 W_b1 (256x10) f32 (orig order; unused by k_bonds)
#define WS_BB1    34304     // 16   b_b1 (10, padded)
#define WS_WATOM  34560     // 4096 W_atom (16x256) f32
#define WS_WTIME  38656     // 256
#define WS_BTIME  38912     // 256
#define WS_BATOM  39168     // 256
#define WS_BAT    39424     // 256
#define WS_BSH    39680     // 256
#define WS_BATOMS 39936     // 32
#define WS_T      40000     // 200 (pad to 40448)
#define WS_X      40448     // 160000 (N x 16) f32
#define WT_AT     200448    // 65536 bf16 (32768 slots): W_at^T  [n][k]
#define WT_SH     233216    // 65536 bf16: W_shared^T [n][k]
#define WT_B0     265984    // 65536 bf16: W_b0[:256]^T [n][k]
#define WT_ATOMS  298752    // 8192 bf16 (4096 slots): W_atoms^T [n][k] (32x256)
#define WT_B1     302848    // 4096 bf16 (2048 slots): W_b1^T [n=16 pad][k=256 PERMUTED]
#define WS_H      304896    // N*256 fp8 bytes = 640,000 float slots
#define WS_END_FLOATS (WS_H + (N_NODES * S_DIM) / 4)   // 944,896 floats ≈ 3.78 MB

// fp8-h storage permutation: storage index S (0..255) -> original channel.
// Chosen so k_node's epilogue lane (wave w, l16) packs acc[c][r] (c=0..3,
// channels w*64 + c*16 + l16) into ONE dword at byte offset w*64 + l16*4.
#define CHAN(S) ((((S) >> 6) << 6) + (((S) & 3) << 4) + (((S) & 63) >> 2))

// ---------------- output layout (element offsets) ----------------
#define O_CPRED 0        // (N,3)
#define O_CEPS  30000    // (N,3)
#define O_APRED 60000    // (N,16)
#define O_AEPS  220000   // (N,16)
#define O_BPRED 380000   // (EG,5)
#define O_BEPS  2880000  // (EG,5)
#define O_DL    5380000  // (EL,)
#define O_RNL   5540000  // (EL,3)
#define O_AG    6020000  // (EG,)
#define O_RNG   6520000  // (EG,3)

__device__ __forceinline__ float b2f(bf16 v) { return __bfloat162float(v); }
__device__ __forceinline__ bf16  f2b(float v) { return __float2bfloat16(v); }
__device__ __forceinline__ unsigned short bbits(float v) {
    bf16 b = f2b(v);
    return *reinterpret_cast<unsigned short*>(&b);
}
__device__ __forceinline__ float ldin(const void* p, int idx, int isf32) {
    return isf32 ? ((const float*)p)[idx] : b2f(((const bf16*)p)[idx]);
}
__device__ __forceinline__ void stout(void* out, int f32o, size_t idx, float v) {
    if (f32o) ((float*)out)[idx] = v;
    else      ((bf16*)out)[idx]  = f2b(v);
}
// fast silu: x * rcp(1 + exp(-x)); v_rcp_f32 ~1 ulp — far below bf16 rounding
__device__ __forceinline__ float silu(float p) {
    return p * __builtin_amdgcn_rcpf(1.0f + __expf(-p));
}

// ---------------- dtype sniff: t ~ U(0,1) ----------------
__global__ void k_sniff(const void* __restrict__ t, float* __restrict__ ws) {
    __shared__ int cnt;
    if (threadIdx.x == 0) cnt = 0;
    __syncthreads();
    if (threadIdx.x < 200) {
        unsigned short v = ((const unsigned short*)t)[threadIdx.x];
        if (v >= 0x4000) atomicAdd(&cnt, 1);
    }
    __syncthreads();
    if (threadIdx.x == 0) ws[WS_FLAG] = (cnt > 10) ? 1.0f : 0.0f;
}

// ---------------- canonicalize inputs; build transposed/permuted weights -----
__global__ void k_prep(const void* __restrict__ x, const void* __restrict__ tt,
                       const void* __restrict__ pos,
                       const void* __restrict__ W_time, const void* __restrict__ b_time,
                       const void* __restrict__ W_atom, const void* __restrict__ b_atom,
                       const void* __restrict__ W_at, const void* __restrict__ b_at,
                       const void* __restrict__ W_shared, const void* __restrict__ b_shared,
                       const void* __restrict__ W_b0, const void* __restrict__ b_b0,
                       const void* __restrict__ W_b1, const void* __restrict__ b_b1,
                       const void* __restrict__ W_atoms, const void* __restrict__ b_atoms,
                       float* __restrict__ ws) {
    const int t = blockIdx.x * blockDim.x + threadIdx.x;  // 640*256 = 163840
    const int f = ws[WS_FLAG] != 0.0f;
    if (t < 65536) {
        // transpose to bf16: WT[n][k] = W[k][n];  t = n*256 + k
        const int n = t >> 8, k = t & 255;
        ((unsigned short*)(ws + WT_AT))[t] = bbits(ldin(W_at,     k * 256 + n, f));
        ((unsigned short*)(ws + WT_SH))[t] = bbits(ldin(W_shared, k * 256 + n, f));
        ((unsigned short*)(ws + WT_B0))[t] = bbits(ldin(W_b0,     k * 256 + n, f));
    }
    if (t < 160000) ws[WS_X + t] = ldin(x, t, f);
    if (t < 30000)  ws[WS_POSC + t] = ldin(pos, t, f);
    if (t < 8192) {
        const int n = t >> 8, k = t & 255;   // W_atoms is (256,32)
        ((unsigned short*)(ws + WT_ATOMS))[t] = bbits(ldin(W_atoms, k * 32 + n, f));
    }
    if (t < 4096) {
        // W_b1^T [n=16 (10 valid)][k=256 in PERMUTED storage order]
        const int n = t >> 8, k = t & 255;
        ((unsigned short*)(ws + WT_B1))[t] =
            (n < 10) ? bbits(ldin(W_b1, CHAN(k) * 10 + n, f)) : 0;
        ws[WS_WATOM + t] = ldin(W_atom, t, f);
    }
    if (t < 2560)   ws[WS_WB1 + t] = ldin(W_b1, t, f);
    if (t < 800)    ws[WS_SUMS + t] = 0.0f;
    if (t < 256) {
        ws[WS_WD + t]    = ldin(W_b0, 65536 + CHAN(t), f);  // permuted wd
        ws[WS_BB0 + t]   = ldin(b_b0, CHAN(t), f);          // permuted b_b0
        ws[WS_WTIME + t] = ldin(W_time, t, f);
        ws[WS_BTIME + t] = ldin(b_time, t, f);
        ws[WS_BATOM + t] = ldin(b_atom, t, f);
        ws[WS_BAT + t]   = ldin(b_at, t, f);
        ws[WS_BSH + t]   = ldin(b_shared, t, f);
    }
    if (t < 200) ws[WS_T + t] = ldin(tt, t, f);
    if (t < 32)  ws[WS_BATOMS + t] = ldin(b_atoms, t, f);
    if (t < 16)  ws[WS_BB1 + t] = (t < 10) ? ldin(b_b1, t, f) : 0.0f;
}

// ---------------- scatter-add pos sums + counts ----------------
__global__ void k_scatter(const int* __restrict__ batch, float* __restrict__ ws) {
    int n = blockIdx.x * blockDim.x + threadIdx.x;
    if (n >= N_NODES) return;
    int b = batch[n];
    atomicAdd(&ws[WS_SUMS + b * 4 + 0], ws[WS_POSC + n * 3 + 0]);
    atomicAdd(&ws[WS_SUMS + b * 4 + 1], ws[WS_POSC + n * 3 + 1]);
    atomicAdd(&ws[WS_SUMS + b * 4 + 2], ws[WS_POSC + n * 3 + 2]);
    atomicAdd(&ws[WS_SUMS + b * 4 + 3], 1.0f);
}

// ---------------- center positions; emit coords_pred / coords_eps0 ----------
__global__ void k_center(const int* __restrict__ batch, float* __restrict__ ws,
                         void* __restrict__ out) {
    int n = blockIdx.x * blockDim.x + threadIdx.x;
    if (n >= N_NODES) return;
    const int f32o = ws[WS_FLAG] != 0.0f;
    int b = batch[n];
    float cnt = fmaxf(ws[WS_SUMS + b * 4 + 3], 1.0f);
    float inv = 1.0f / cnt;
#pragma unroll
    for (int k = 0; k < 3; ++k) {
        float p = ws[WS_POSC + n * 3 + k] - ws[WS_SUMS + b * 4 + k] * inv;
        ws[WS_POSC + n * 3 + k] = p;
        stout(out, f32o, O_CPRED + n * 3 + k, p);
        stout(out, f32o, O_CEPS + n * 3 + k, 0.0f);
    }
}

// ---------------- MFMA node pipeline: 16 rows/block, 4 waves, 625 blocks ------
__global__ __launch_bounds__(256) void k_node(
    const int* __restrict__ batch, const float* __restrict__ ws,
    unsigned int* __restrict__ h_out, void* __restrict__ out) {
    __shared__ unsigned short actA[16][APAD];
    __shared__ unsigned short actB[16][APAD];
    const int tid = threadIdx.x;
    const int wave = tid >> 6, lane = tid & 63;
    const int quad = lane >> 4, l16 = lane & 15;
    const int row0 = blockIdx.x * 16;   // 625 * 16 == 10000 exactly

    // ---- stage 0 (VALU f32): s0 = x@W_atom + b_atom + t[batch]*W_time + b_time
    {
        const int r = tid >> 4;            // 16 rows, 16 threads/row
        const int c0 = (tid & 15) * 16;    // 16 cols/thread
        const int g = row0 + r;
        float tb = ws[WS_T + batch[g]];
        float xr[16];
#pragma unroll
        for (int k = 0; k < 16; ++k) xr[k] = ws[WS_X + g * 16 + k];
        for (int cc = 0; cc < 16; cc += 4) {
            const int c = c0 + cc;
            float a0 = ws[WS_BATOM + c + 0] + tb * ws[WS_WTIME + c + 0] + ws[WS_BTIME + c + 0];
            float a1 = ws[WS_BATOM + c + 1] + tb * ws[WS_WTIME + c + 1] + ws[WS_BTIME + c + 1];
            float a2 = ws[WS_BATOM + c + 2] + tb * ws[WS_WTIME + c + 2] + ws[WS_BTIME + c + 2];
            float a3 = ws[WS_BATOM + c + 3] + tb * ws[WS_WTIME + c + 3] + ws[WS_BTIME + c + 3];
#pragma unroll
            for (int k = 0; k < 16; ++k) {
                float4 w4 = *(const float4*)(ws + WS_WATOM + k * S_DIM + c);
                a0 += xr[k] * w4.x; a1 += xr[k] * w4.y;
                a2 += xr[k] * w4.z; a3 += xr[k] * w4.w;
            }
            actA[r][c + 0] = bbits(a0); actA[r][c + 1] = bbits(a1);
            actA[r][c + 2] = bbits(a2); actA[r][c + 3] = bbits(a3);
        }
    }
    __syncthreads();

    const unsigned short* wt_at = (const unsigned short*)(ws + WT_AT);
    const unsigned short* wt_sh = (const unsigned short*)(ws + WT_SH);
    const unsigned short* wt_b0 = (const unsigned short*)(ws + WT_B0);
    const unsigned short* wt_am = (const unsigned short*)(ws + WT_ATOMS);
    const int n0 = wave * 64;

    // ---- layer 1: actB = actA @ W_at + b_at
    {
        f32x4 acc[4] = {};
        for (int kk = 0; kk < S_DIM; kk += 32) {
            const int k = kk + quad * 8;
            bf16x8 a = *(const bf16x8*)&actA[l16][k];
#pragma unroll
            for (int nt = 0; nt < 4; ++nt) {
                bf16x8 b = *(const bf16x8*)(wt_at + (size_t)(n0 + nt * 16 + l16) * S_DIM + k);
                acc[nt] = __builtin_amdgcn_mfma_f32_16x16x32_bf16(a, b, acc[nt], 0, 0, 0);
            }
        }
#pragma unroll
        for (int nt = 0; nt < 4; ++nt) {
            const int n = n0 + nt * 16 + l16;
            const float bv = ws[WS_BAT + n];
#pragma unroll
            for (int r = 0; r < 4; ++r)
                actB[quad * 4 + r][n] = bbits(acc[nt][r] + bv);
        }
    }
    __syncthreads();

    // ---- layer 2: actA = silu(actB @ W_shared + b_shared)
    {
        f32x4 acc[4] = {};
        for (int kk = 0; kk < S_DIM; kk += 32) {
            const int k = kk + quad * 8;
            bf16x8 a = *(const bf16x8*)&actB[l16][k];
#pragma unroll
            for (int nt = 0; nt < 4; ++nt) {
                bf16x8 b = *(const bf16x8*)(wt_sh + (size_t)(n0 + nt * 16 + l16) * S_DIM + k);
                acc[nt] = __builtin_amdgcn_mfma_f32_16x16x32_bf16(a, b, acc[nt], 0, 0, 0);
            }
        }
        __syncthreads();
#pragma unroll
        for (int nt = 0; nt < 4; ++nt) {
            const int n = n0 + nt * 16 + l16;
            const float bv = ws[WS_BSH + n];
#pragma unroll
            for (int r = 0; r < 4; ++r)
                actA[quad * 4 + r][n] = bbits(silu(acc[nt][r] + bv));
        }
    }
    __syncthreads();

    // ---- layer 3: h = actA @ W_b0[:256], fp8 e4m3 PERMUTED, one dword/row/lane
    {
        f32x4 acc[4] = {};
        for (int kk = 0; kk < S_DIM; kk += 32) {
            const int k = kk + quad * 8;
            bf16x8 a = *(const bf16x8*)&actA[l16][k];
#pragma unroll
            for (int nt = 0; nt < 4; ++nt) {
                bf16x8 b = *(const bf16x8*)(wt_b0 + (size_t)(n0 + nt * 16 + l16) * S_DIM + k);
                acc[nt] = __builtin_amdgcn_mfma_f32_16x16x32_bf16(a, b, acc[nt], 0, 0, 0);
            }
        }
#pragma unroll
        for (int r = 0; r < 4; ++r) {
            const int g = row0 + quad * 4 + r;
            int w = 0;
            w = __builtin_amdgcn_cvt_pk_fp8_f32(acc[0][r], acc[1][r], w, false);
            w = __builtin_amdgcn_cvt_pk_fp8_f32(acc[2][r], acc[3][r], w, true);
            h_out[(size_t)g * 64 + wave * 16 + l16] = (unsigned int)w;
        }
    }

    // ---- layer 4: atoms = actA @ W_atoms + b_atoms (256 -> 32), waves 0,1
    if (wave < 2) {
        f32x4 acc = {};
        const int n = wave * 16 + l16;            // 0..31
        for (int kk = 0; kk < S_DIM; kk += 32) {
            const int k = kk + quad * 8;
            bf16x8 a = *(const bf16x8*)&actA[l16][k];
            bf16x8 b = *(const bf16x8*)(wt_am + (size_t)n * S_DIM + k);
            acc = __builtin_amdgcn_mfma_f32_16x16x32_bf16(a, b, acc, 0, 0, 0);
        }
        const float bv = ws[WS_BATOMS + n];
        const int f32o = ws[WS_FLAG] != 0.0f;
#pragma unroll
        for (int r = 0; r < 4; ++r) {
            const int g = row0 + quad * 4 + r;
            float v = acc[r] + bv;
            if (n < 16) stout(out, f32o, O_AEPS + (size_t)g * 16 + n, v);
            else        stout(out, f32o, O_APRED + (size_t)g * 16 + (n - 16), v);
        }
    }
}

// ---------------- local edge attrs: d_l, rn_l ----------------
__global__ void k_local(const int* __restrict__ ei, const float* __restrict__ ws,
                        void* __restrict__ out) {
    int e = blockIdx.x * blockDim.x + threadIdx.x;
    if (e >= EL_EDGES) return;
    const int f32o = ws[WS_FLAG] != 0.0f;
    const float* posc = ws + WS_POSC;
    int s = ei[e];
    int t = ei[EL_EDGES + e];
    float rx = posc[t * 3 + 0] - posc[s * 3 + 0];
    float ry = posc[t * 3 + 1] - posc[s * 3 + 1];
    float rz = posc[t * 3 + 2] - posc[s * 3 + 2];
    float dsq = rx * rx + ry * ry + rz * rz;
    float d = sqrtf(fmaxf(dsq, 1e-6f));
    float inv = 1.0f / d;
    stout(out, f32o, O_DL + e, d);
    stout(out, f32o, O_RNL + e * 3 + 0, rx * inv);
    stout(out, f32o, O_RNL + e * 3 + 1, ry * inv);
    stout(out, f32o, O_RNL + e * 3 + 2, rz * inv);
}

// ---------------- global edges, MFMA-tiled, fp8 h gathers --------------------
// 16 edges/wave; lane l16 = edge (A-row m); quad = k-chunk. h rows are fp8
// (256 B: 2.5 MB table fits per-XCD L2) in permuted storage order matching
// wd/bb0/WT_B1. Gathers are dwordx2; decode via native cvt_pk_f32_fp8.
__global__ __launch_bounds__(256, 4) void k_bonds(const int* __restrict__ ei,
                                                  const float* __restrict__ ws,
                                                  const unsigned char* __restrict__ h,
                                                  void* __restrict__ out) {
    const int wave = threadIdx.x >> 6, lane = threadIdx.x & 63;
    const int quad = lane >> 4, l16 = lane & 15;
    const int e0 = blockIdx.x * 64 + wave * 16;
    const int f32o = ws[WS_FLAG] != 0.0f;

    const int e = e0 + l16;
    const bool ev = e < EG_EDGES;
    const int ec = ev ? e : (EG_EDGES - 1);
    const int j = ei[ec];             // src
    const int i = ei[EG_EDGES + ec];  // tgt

    // ---- issue all h gathers (16 independent global_load_dwordx2) ----
    const unsigned char* __restrict__ hi = h + (size_t)i * 256 + quad * 8;
    const unsigned char* __restrict__ hj = h + (size_t)j * 256 + quad * 8;
    uint2 ua[8], ub[8];
#pragma unroll
    for (int t = 0; t < 8; ++t) ua[t] = *(const uint2*)(hi + t * 32);
#pragma unroll
    for (int t = 0; t < 8; ++t) ub[t] = *(const uint2*)(hj + t * 32);

    // ---- geometry while gathers are in flight ----
    const float* posc = ws + WS_POSC;
    float pix = posc[i * 3 + 0], piy = posc[i * 3 + 1], piz = posc[i * 3 + 2];
    float pjx = posc[j * 3 + 0], pjy = posc[j * 3 + 1], pjz = posc[j * 3 + 2];
    float rx = pix - pjx, ry = piy - pjy, rz = piz - pjz;
    float dsq = rx * rx + ry * ry + rz * rz;
    float d = sqrtf(dsq);  // bonds distance: no clip in reference

    if (quad == 0 && ev) {
        float ag = pix * pjx + piy * pjy + piz * pjz;
        float inv = 1.0f / sqrtf(fmaxf(dsq, 1e-6f));
        stout(out, f32o, O_AG + e, ag);
        stout(out, f32o, O_RNG + (size_t)e * 3 + 0, rx * inv);
        stout(out, f32o, O_RNG + (size_t)e * 3 + 1, ry * inv);
        stout(out, f32o, O_RNG + (size_t)e * 3 + 2, rz * inv);
    }

    const float* __restrict__ wd  = ws + WS_WD;   // permuted
    const float* __restrict__ bb0 = ws + WS_BB0;  // permuted
    const unsigned short* __restrict__ wb1t = (const unsigned short*)(ws + WT_B1);

    f32x4 acc = {};
#pragma unroll
    for (int t = 0; t < 8; ++t) {
        const int k = t * 32 + quad * 8;   // storage index base
        float4 wA = *(const float4*)(wd + k);
        float4 wB = *(const float4*)(wd + k + 4);
        float4 bA = *(const float4*)(bb0 + k);
        float4 bB = *(const float4*)(bb0 + k + 4);
        f32x2 a01 = __builtin_amdgcn_cvt_pk_f32_fp8((int)ua[t].x, false);
        f32x2 a23 = __builtin_amdgcn_cvt_pk_f32_fp8((int)ua[t].x, true);
        f32x2 a45 = __builtin_amdgcn_cvt_pk_f32_fp8((int)ua[t].y, false);
        f32x2 a67 = __builtin_amdgcn_cvt_pk_f32_fp8((int)ua[t].y, true);
        f32x2 b01 = __builtin_amdgcn_cvt_pk_f32_fp8((int)ub[t].x, false);
        f32x2 b23 = __builtin_amdgcn_cvt_pk_f32_fp8((int)ub[t].x, true);
        f32x2 b45 = __builtin_amdgcn_cvt_pk_f32_fp8((int)ub[t].y, false);
        f32x2 b67 = __builtin_amdgcn_cvt_pk_f32_fp8((int)ub[t].y, true);
        union { bf16x8 v; unsigned short s[8]; } af;
        af.s[0] = bbits(silu(a01.x + b01.x + fmaf(d, wA.x, bA.x)));
        af.s[1] = bbits(silu(a01.y + b01.y + fmaf(d, wA.y, bA.y)));
        af.s[2] = bbits(silu(a23.x + b23.x + fmaf(d, wA.z, bA.z)));
        af.s[3] = bbits(silu(a23.y + b23.y + fmaf(d, wA.w, bA.w)));
        af.s[4] = bbits(silu(a45.x + b45.x + fmaf(d, wB.x, bB.x)));
        af.s[5] = bbits(silu(a45.y + b45.y + fmaf(d, wB.y, bB.y)));
        af.s[6] = bbits(silu(a67.x + b67.x + fmaf(d, wB.z, bB.z)));
        af.s[7] = bbits(silu(a67.y + b67.y + fmaf(d, wB.w, bB.w)));
        bf16x8 bfr = *(const bf16x8*)(wb1t + (size_t)l16 * S_DIM + k);
        acc = __builtin_amdgcn_mfma_f32_16x16x32_bf16(af.v, bfr, acc, 0, 0, 0);
    }

    // epilogue: lane col n=l16 (10 valid), rows = e0 + quad*4 + r
    if (l16 < 10) {
        const float bv = ws[WS_BB1 + l16];
#pragma unroll
        for (int r = 0; r < 4; ++r) {
            const int er = e0 + quad * 4 + r;
            if (er < EG_EDGES) {
                float v = acc[r] + bv;
                if (l16 < 5) stout(out, f32o, O_BPRED + (size_t)er * 5 + l16, v);
                else         stout(out, f32o, O_BEPS + (size_t)er * 5 + (l16 - 5), v);
            }
        }
    }
}

extern "C" void kernel_launch(void* const* d_in, const int* in_sizes, int n_in,
                              void* d_out, int out_size, void* d_ws, size_t ws_size,
                              hipStream_t stream) {
    const void* x        = d_in[0];
    const void* t        = d_in[1];
    const void* pos      = d_in[2];
    const int*  eil      = (const int*)d_in[3];
    const int*  eig      = (const int*)d_in[4];
    const int*  batch    = (const int*)d_in[6];
    const void* W_time   = d_in[7];
    const void* b_time   = d_in[8];
    const void* W_atom   = d_in[9];
    const void* b_atom   = d_in[10];
    const void* W_at     = d_in[11];
    const void* b_at     = d_in[12];
    const void* W_shared = d_in[13];
    const void* b_shared = d_in[14];
    const void* W_b0     = d_in[15];
    const void* b_b0     = d_in[16];
    const void* W_b1     = d_in[17];
    const void* b_b1     = d_in[18];
    const void* W_atoms  = d_in[20];
    const void* b_atoms  = d_in[21];
    (void)in_sizes; (void)n_in; (void)out_size;

    const size_t NEED = (size_t)WS_END_FLOATS * sizeof(float);
    if (ws_size < NEED) return;

    float* ws = (float*)d_ws;
    unsigned int* hbuf = (unsigned int*)(ws + WS_H);

    k_sniff<<<1, 256, 0, stream>>>(t, ws);
    k_prep<<<640, 256, 0, stream>>>(x, t, pos, W_time, b_time, W_atom, b_atom,
                                    W_at, b_at, W_shared, b_shared, W_b0, b_b0,
                                    W_b1, b_b1, W_atoms, b_atoms, ws);
    k_scatter<<<(N_NODES + 255) / 256, 256, 0, stream>>>(batch, ws);
    k_center<<<(N_NODES + 255) / 256, 256, 0, stream>>>(batch, ws, d_out);
    k_node<<<N_NODES / 16, 256, 0, stream>>>(batch, ws, hbuf, d_out);
    k_local<<<(EL_EDGES + 255) / 256, 256, 0, stream>>>(eil, ws, d_out);
    k_bonds<<<(EG_EDGES + 63) / 64, 256, 0, stream>>>(eig, ws,
                                                      (const unsigned char*)hbuf, d_out);
}

// Round 9
// 250.681 us; speedup vs baseline: 1.2600x; 1.2600x over previous
//
#include <hip/hip_runtime.h>
#include <hip/hip_bf16.h>

typedef __hip_bfloat16 bf16;
typedef short bf16x8 __attribute__((ext_vector_type(8)));
typedef float f32x4 __attribute__((ext_vector_type(4)));
typedef float f32x2 __attribute__((ext_vector_type(2)));

#define N_NODES  10000
#define G_GRAPHS 200
#define EL_EDGES 160000
#define EG_EDGES 500000
#define S_DIM    256
#define APAD     264   // k_node LDS row stride in bf16

// ---------------- workspace layout (float offsets) ----------------
#define WS_FLAG   0         // input dtype flag (0=bf16, 1=f32), written by k_prep
#define WS_POSC   1024      // 30000: centered positions f32 (written by k_pos)
#define WS_WD     31232     // 256  W_b0 row 256, PERMUTED to storage order
#define WS_BB0    31488     // 256  b_b0, PERMUTED to storage order
#define WS_BB1    34304     // 16   b_b1 (10, padded)
#define WS_WATOM  34560     // 4096 W_atom (16x256) f32
#define WS_WTIME  38656     // 256
#define WS_BTIME  38912     // 256
#define WS_BATOM  39168     // 256
#define WS_BAT    39424     // 256
#define WS_BSH    39680     // 256
#define WS_BATOMS 39936     // 32
#define WS_T      40000     // 200 (pad to 40448)
#define WS_X      40448     // 160000 (N x 16) f32
#define WT_AT     200448    // 65536 bf16 (32768 slots): W_at^T  [n][k]
#define WT_SH     233216    // 65536 bf16: W_shared^T [n][k]
#define WT_B0     265984    // 65536 bf16: W_b0[:256]^T [n][k]
#define WT_ATOMS  298752    // 8192 bf16 (4096 slots): W_atoms^T [n][k] (32x256)
#define WT_B1     302848    // 4096 bf16 (2048 slots): W_b1^T [n=16 pad][k=256 PERMUTED]
#define WS_H      304896    // N*256 fp8 bytes = 640,000 float slots
#define WS_END_FLOATS (WS_H + (N_NODES * S_DIM) / 4)   // 944,896 floats ≈ 3.78 MB

// fp8-h storage permutation: storage index S -> original channel, and inverse.
#define CHAN(S)    ((((S) >> 6) << 6) + (((S) & 3) << 4) + (((S) & 63) >> 2))
#define CHANINV(k) ((((k) >> 6) << 6) + (((k) & 15) << 2) + (((k) >> 4) & 3))

// ---------------- output layout (element offsets) ----------------
#define O_CPRED 0        // (N,3)
#define O_CEPS  30000    // (N,3)
#define O_APRED 60000    // (N,16)
#define O_AEPS  220000   // (N,16)
#define O_BPRED 380000   // (EG,5)
#define O_BEPS  2880000  // (EG,5)
#define O_DL    5380000  // (EL,)
#define O_RNL   5540000  // (EL,3)
#define O_AG    6020000  // (EG,)
#define O_RNG   6520000  // (EG,3)

__device__ __forceinline__ float b2f(bf16 v) { return __bfloat162float(v); }
__device__ __forceinline__ bf16  f2b(float v) { return __float2bfloat16(v); }
__device__ __forceinline__ unsigned short bbits(float v) {
    bf16 b = f2b(v);
    return *reinterpret_cast<unsigned short*>(&b);
}
__device__ __forceinline__ float ldin(const void* p, int idx, int isf32) {
    return isf32 ? ((const float*)p)[idx] : b2f(((const bf16*)p)[idx]);
}
__device__ __forceinline__ void stout(void* out, int f32o, size_t idx, float v) {
    if (f32o) ((float*)out)[idx] = v;
    else      ((bf16*)out)[idx]  = f2b(v);
}
__device__ __forceinline__ float silu(float p) {
    return p * __builtin_amdgcn_rcpf(1.0f + __expf(-p));
}
// dtype sniff inline: t ~ U(0,1). bf16 halfwords all < 0x4000; f32 low-mantissa
// halfwords uniform random. 32 halfwords => P(false bf16) ~ 0.25^16 ≈ 2e-10.
__device__ __forceinline__ int dtype_f32(const void* tt) {
    const unsigned short* q = (const unsigned short*)tt;
    int c = 0;
#pragma unroll
    for (int z = 0; z < 32; ++z) c += (q[z] >= 0x4000) ? 1 : 0;
    return c > 0;
}

// ---------------- canonicalize inputs; build transposed/permuted weights -----
// Transposes are read-coalesced / write-scattered (stores don't stall).
__global__ void k_prep(const void* __restrict__ x, const void* __restrict__ tt,
                       const void* __restrict__ W_time, const void* __restrict__ b_time,
                       const void* __restrict__ W_atom, const void* __restrict__ b_atom,
                       const void* __restrict__ W_at, const void* __restrict__ b_at,
                       const void* __restrict__ W_shared, const void* __restrict__ b_shared,
                       const void* __restrict__ W_b0, const void* __restrict__ b_b0,
                       const void* __restrict__ W_b1, const void* __restrict__ b_b1,
                       const void* __restrict__ W_atoms, const void* __restrict__ b_atoms,
                       float* __restrict__ ws) {
    const int t = blockIdx.x * blockDim.x + threadIdx.x;  // 640*256 = 163840
    const int f = dtype_f32(tt);
    if (t == 0) ws[WS_FLAG] = f ? 1.0f : 0.0f;
    if (t < 65536) {
        // read coalesced W[k][n] (t = k*256+n), scatter-write WT[n][k]
        const int k = t >> 8, n = t & 255;
        ((unsigned short*)(ws + WT_AT))[n * 256 + k] = bbits(ldin(W_at, t, f));
        ((unsigned short*)(ws + WT_SH))[n * 256 + k] = bbits(ldin(W_shared, t, f));
        ((unsigned short*)(ws + WT_B0))[n * 256 + k] = bbits(ldin(W_b0, t, f));
    }
    if (t < 160000) ws[WS_X + t] = ldin(x, t, f);
    if (t < 8192) {
        const int k = t >> 5, n = t & 31;   // W_atoms (256,32), t = k*32+n
        ((unsigned short*)(ws + WT_ATOMS))[n * 256 + k] = bbits(ldin(W_atoms, t, f));
    }
    if (t < 4096) ws[WS_WATOM + t] = ldin(W_atom, t, f);
    if (t < 2560) {
        // W_b1 (256,10), t = k*10+n -> WT_B1[n][CHANINV(k)]
        const int k = t / 10, n = t - k * 10;
        ((unsigned short*)(ws + WT_B1))[n * 256 + CHANINV(k)] = bbits(ldin(W_b1, t, f));
    } else if (t < 4096) {
        ((unsigned short*)(ws + WT_B1))[t] = 0;   // pad rows n=10..15
    }
    if (t < 256) {
        ws[WS_WD + t]    = ldin(W_b0, 65536 + CHAN(t), f);  // permuted wd
        ws[WS_BB0 + t]   = ldin(b_b0, CHAN(t), f);          // permuted b_b0
        ws[WS_WTIME + t] = ldin(W_time, t, f);
        ws[WS_BTIME + t] = ldin(b_time, t, f);
        ws[WS_BATOM + t] = ldin(b_atom, t, f);
        ws[WS_BAT + t]   = ldin(b_at, t, f);
        ws[WS_BSH + t]   = ldin(b_shared, t, f);
    }
    if (t < 200) ws[WS_T + t] = ldin(tt, t, f);
    if (t < 32)  ws[WS_BATOMS + t] = ldin(b_atoms, t, f);
    if (t < 16)  ws[WS_BB1 + t] = (t < 10) ? ldin(b_b1, t, f) : 0.0f;
}

// ---------------- per-graph mean + center (sorted batch, no atomics) ----------
// one block per graph: binary-search node range, block-reduce, center, emit.
__global__ void k_pos(const void* __restrict__ pos, const int* __restrict__ batch,
                      float* __restrict__ ws, void* __restrict__ out) {
    const int g = blockIdx.x;
    const int f32o = ws[WS_FLAG] != 0.0f;
    __shared__ int s_lo, s_hi;
    __shared__ float wsum[4][3];
    __shared__ float mean[3];
    if (threadIdx.x == 0) {
        int lo = 0, hi = N_NODES;
        while (lo < hi) { int m = (lo + hi) >> 1; if (batch[m] < g) lo = m + 1; else hi = m; }
        s_lo = lo;
        int lo2 = lo; hi = N_NODES;
        while (lo2 < hi) { int m = (lo2 + hi) >> 1; if (batch[m] < g + 1) lo2 = m + 1; else hi = m; }
        s_hi = lo2;
    }
    __syncthreads();
    const int lo = s_lo, hi = s_hi, cnt = hi - lo;
    float sx = 0.f, sy = 0.f, sz = 0.f;
    for (int n = lo + threadIdx.x; n < hi; n += 256) {
        sx += ldin(pos, n * 3 + 0, f32o);
        sy += ldin(pos, n * 3 + 1, f32o);
        sz += ldin(pos, n * 3 + 2, f32o);
    }
#pragma unroll
    for (int off = 32; off > 0; off >>= 1) {
        sx += __shfl_down(sx, off);
        sy += __shfl_down(sy, off);
        sz += __shfl_down(sz, off);
    }
    if ((threadIdx.x & 63) == 0) {
        wsum[threadIdx.x >> 6][0] = sx;
        wsum[threadIdx.x >> 6][1] = sy;
        wsum[threadIdx.x >> 6][2] = sz;
    }
    __syncthreads();
    if (threadIdx.x == 0) {
        float inv = 1.0f / (float)max(cnt, 1);
        mean[0] = (wsum[0][0] + wsum[1][0] + wsum[2][0] + wsum[3][0]) * inv;
        mean[1] = (wsum[0][1] + wsum[1][1] + wsum[2][1] + wsum[3][1]) * inv;
        mean[2] = (wsum[0][2] + wsum[1][2] + wsum[2][2] + wsum[3][2]) * inv;
    }
    __syncthreads();
    for (int n = lo + threadIdx.x; n < hi; n += 256) {
#pragma unroll
        for (int k = 0; k < 3; ++k) {
            float p = ldin(pos, n * 3 + k, f32o) - mean[k];
            ws[WS_POSC + n * 3 + k] = p;
            stout(out, f32o, O_CPRED + n * 3 + k, p);  // coords_pred = pos_c (v==0)
            stout(out, f32o, O_CEPS + n * 3 + k, 0.0f);
        }
    }
}

// ---------------- MFMA node pipeline: 16 rows/block, 4 waves, 625 blocks ------
__global__ __launch_bounds__(256) void k_node(
    const int* __restrict__ batch, const float* __restrict__ ws,
    unsigned int* __restrict__ h_out, void* __restrict__ out) {
    __shared__ unsigned short actA[16][APAD];
    __shared__ unsigned short actB[16][APAD];
    const int tid = threadIdx.x;
    const int wave = tid >> 6, lane = tid & 63;
    const int quad = lane >> 4, l16 = lane & 15;
    const int row0 = blockIdx.x * 16;   // 625 * 16 == 10000 exactly

    // ---- stage 0 (VALU f32): s0 = x@W_atom + b_atom + t[batch]*W_time + b_time
    {
        const int r = tid >> 4;            // 16 rows, 16 threads/row
        const int c0 = (tid & 15) * 16;    // 16 cols/thread
        const int g = row0 + r;
        float tb = ws[WS_T + batch[g]];
        float xr[16];
#pragma unroll
        for (int k = 0; k < 16; ++k) xr[k] = ws[WS_X + g * 16 + k];
        for (int cc = 0; cc < 16; cc += 4) {
            const int c = c0 + cc;
            float a0 = ws[WS_BATOM + c + 0] + tb * ws[WS_WTIME + c + 0] + ws[WS_BTIME + c + 0];
            float a1 = ws[WS_BATOM + c + 1] + tb * ws[WS_WTIME + c + 1] + ws[WS_BTIME + c + 1];
            float a2 = ws[WS_BATOM + c + 2] + tb * ws[WS_WTIME + c + 2] + ws[WS_BTIME + c + 2];
            float a3 = ws[WS_BATOM + c + 3] + tb * ws[WS_WTIME + c + 3] + ws[WS_BTIME + c + 3];
#pragma unroll
            for (int k = 0; k < 16; ++k) {
                float4 w4 = *(const float4*)(ws + WS_WATOM + k * S_DIM + c);
                a0 += xr[k] * w4.x; a1 += xr[k] * w4.y;
                a2 += xr[k] * w4.z; a3 += xr[k] * w4.w;
            }
            actA[r][c + 0] = bbits(a0); actA[r][c + 1] = bbits(a1);
            actA[r][c + 2] = bbits(a2); actA[r][c + 3] = bbits(a3);
        }
    }
    __syncthreads();

    const unsigned short* wt_at = (const unsigned short*)(ws + WT_AT);
    const unsigned short* wt_sh = (const unsigned short*)(ws + WT_SH);
    const unsigned short* wt_b0 = (const unsigned short*)(ws + WT_B0);
    const unsigned short* wt_am = (const unsigned short*)(ws + WT_ATOMS);
    const int n0 = wave * 64;

    // ---- layer 1: actB = actA @ W_at + b_at
    {
        f32x4 acc[4] = {};
        for (int kk = 0; kk < S_DIM; kk += 32) {
            const int k = kk + quad * 8;
            bf16x8 a = *(const bf16x8*)&actA[l16][k];
#pragma unroll
            for (int nt = 0; nt < 4; ++nt) {
                bf16x8 b = *(const bf16x8*)(wt_at + (size_t)(n0 + nt * 16 + l16) * S_DIM + k);
                acc[nt] = __builtin_amdgcn_mfma_f32_16x16x32_bf16(a, b, acc[nt], 0, 0, 0);
            }
        }
#pragma unroll
        for (int nt = 0; nt < 4; ++nt) {
            const int n = n0 + nt * 16 + l16;
            const float bv = ws[WS_BAT + n];
#pragma unroll
            for (int r = 0; r < 4; ++r)
                actB[quad * 4 + r][n] = bbits(acc[nt][r] + bv);
        }
    }
    __syncthreads();

    // ---- layer 2: actA = silu(actB @ W_shared + b_shared)
    {
        f32x4 acc[4] = {};
        for (int kk = 0; kk < S_DIM; kk += 32) {
            const int k = kk + quad * 8;
            bf16x8 a = *(const bf16x8*)&actB[l16][k];
#pragma unroll
            for (int nt = 0; nt < 4; ++nt) {
                bf16x8 b = *(const bf16x8*)(wt_sh + (size_t)(n0 + nt * 16 + l16) * S_DIM + k);
                acc[nt] = __builtin_amdgcn_mfma_f32_16x16x32_bf16(a, b, acc[nt], 0, 0, 0);
            }
        }
        __syncthreads();
#pragma unroll
        for (int nt = 0; nt < 4; ++nt) {
            const int n = n0 + nt * 16 + l16;
            const float bv = ws[WS_BSH + n];
#pragma unroll
            for (int r = 0; r < 4; ++r)
                actA[quad * 4 + r][n] = bbits(silu(acc[nt][r] + bv));
        }
    }
    __syncthreads();

    // ---- layer 3: h = actA @ W_b0[:256], fp8 e4m3 PERMUTED, one dword/row/lane
    {
        f32x4 acc[4] = {};
        for (int kk = 0; kk < S_DIM; kk += 32) {
            const int k = kk + quad * 8;
            bf16x8 a = *(const bf16x8*)&actA[l16][k];
#pragma unroll
            for (int nt = 0; nt < 4; ++nt) {
                bf16x8 b = *(const bf16x8*)(wt_b0 + (size_t)(n0 + nt * 16 + l16) * S_DIM + k);
                acc[nt] = __builtin_amdgcn_mfma_f32_16x16x32_bf16(a, b, acc[nt], 0, 0, 0);
            }
        }
#pragma unroll
        for (int r = 0; r < 4; ++r) {
            const int g = row0 + quad * 4 + r;
            int w = 0;
            w = __builtin_amdgcn_cvt_pk_fp8_f32(acc[0][r], acc[1][r], w, false);
            w = __builtin_amdgcn_cvt_pk_fp8_f32(acc[2][r], acc[3][r], w, true);
            h_out[(size_t)g * 64 + wave * 16 + l16] = (unsigned int)w;
        }
    }

    // ---- layer 4: atoms = actA @ W_atoms + b_atoms (256 -> 32), waves 0,1
    if (wave < 2) {
        f32x4 acc = {};
        const int n = wave * 16 + l16;            // 0..31
        for (int kk = 0; kk < S_DIM; kk += 32) {
            const int k = kk + quad * 8;
            bf16x8 a = *(const bf16x8*)&actA[l16][k];
            bf16x8 b = *(const bf16x8*)(wt_am + (size_t)n * S_DIM + k);
            acc = __builtin_amdgcn_mfma_f32_16x16x32_bf16(a, b, acc, 0, 0, 0);
        }
        const float bv = ws[WS_BATOMS + n];
        const int f32o = ws[WS_FLAG] != 0.0f;
#pragma unroll
        for (int r = 0; r < 4; ++r) {
            const int g = row0 + quad * 4 + r;
            float v = acc[r] + bv;
            if (n < 16) stout(out, f32o, O_AEPS + (size_t)g * 16 + n, v);
            else        stout(out, f32o, O_APRED + (size_t)g * 16 + (n - 16), v);
        }
    }
}

// ---------------- local edge attrs: d_l, rn_l ----------------
__global__ void k_local(const int* __restrict__ ei, const float* __restrict__ ws,
                        void* __restrict__ out) {
    int e = blockIdx.x * blockDim.x + threadIdx.x;
    if (e >= EL_EDGES) return;
    const int f32o = ws[WS_FLAG] != 0.0f;
    const float* posc = ws + WS_POSC;
    int s = ei[e];
    int t = ei[EL_EDGES + e];
    float rx = posc[t * 3 + 0] - posc[s * 3 + 0];
    float ry = posc[t * 3 + 1] - posc[s * 3 + 1];
    float rz = posc[t * 3 + 2] - posc[s * 3 + 2];
    float dsq = rx * rx + ry * ry + rz * rz;
    float d = sqrtf(fmaxf(dsq, 1e-6f));
    float inv = 1.0f / d;
    stout(out, f32o, O_DL + e, d);
    stout(out, f32o, O_RNL + e * 3 + 0, rx * inv);
    stout(out, f32o, O_RNL + e * 3 + 1, ry * inv);
    stout(out, f32o, O_RNL + e * 3 + 2, rz * inv);
}

// ---------------- global edges: coalesced LDS-staged fp8 gathers + MFMA -------
// 16 edges/wave. Staging: 8 coalesced global_load_dwordx4 (16 lanes = one
// 256B row; 4 rows/inst) -> ds_write_b128 into per-wave LDS slice (272B row
// stride). Scattered-request count halves vs per-lane gathers (the R5-R8
// invariant this round attacks). Compute reads fragments via ds_read_b64.
__global__ __launch_bounds__(256) void k_bonds(const int* __restrict__ ei,
                                               const float* __restrict__ ws,
                                               const unsigned char* __restrict__ h,
                                               void* __restrict__ out) {
    __shared__ unsigned char sm[4][32][272];   // [wave][row][256B + 16 pad]
    const int wave = threadIdx.x >> 6, lane = threadIdx.x & 63;
    const int quad = lane >> 4, l16 = lane & 15;
    const int e0 = blockIdx.x * 64 + wave * 16;
    const int f32o = ws[WS_FLAG] != 0.0f;

    // ---- stage 32 rows (16 hi + 16 hj) via coalesced loads ----
    uint4 tmp[8];
#pragma unroll
    for (int p = 0; p < 8; ++p) {
        const int row = p * 4 + quad;                    // 0..31
        const int es = e0 + (row & 15);
        const int ecs = es < EG_EDGES ? es : (EG_EDGES - 1);
        const int node = (row < 16) ? ei[EG_EDGES + ecs] : ei[ecs];
        tmp[p] = *(const uint4*)(h + (size_t)node * 256 + l16 * 16);
    }
#pragma unroll
    for (int p = 0; p < 8; ++p) {
        const int row = p * 4 + quad;
        *(uint4*)&sm[wave][row][l16 * 16] = tmp[p];
    }

    // ---- geometry (own edge l16) ----
    const int e = e0 + l16;
    const bool ev = e < EG_EDGES;
    const int ec = ev ? e : (EG_EDGES - 1);
    const int j = ei[ec];             // src
    const int i = ei[EG_EDGES + ec];  // tgt
    const float* posc = ws + WS_POSC;
    float pix = posc[i * 3 + 0], piy = posc[i * 3 + 1], piz = posc[i * 3 + 2];
    float pjx = posc[j * 3 + 0], pjy = posc[j * 3 + 1], pjz = posc[j * 3 + 2];
    float rx = pix - pjx, ry = piy - pjy, rz = piz - pjz;
    float dsq = rx * rx + ry * ry + rz * rz;
    float d = sqrtf(dsq);  // bonds distance: no clip in reference

    if (quad == 0 && ev) {
        float ag = pix * pjx + piy * pjy + piz * pjz;
        float inv = 1.0f / sqrtf(fmaxf(dsq, 1e-6f));
        stout(out, f32o, O_AG + e, ag);
        stout(out, f32o, O_RNG + (size_t)e * 3 + 0, rx * inv);
        stout(out, f32o, O_RNG + (size_t)e * 3 + 1, ry * inv);
        stout(out, f32o, O_RNG + (size_t)e * 3 + 2, rz * inv);
    }

    const float* __restrict__ wd  = ws + WS_WD;   // permuted
    const float* __restrict__ bb0 = ws + WS_BB0;  // permuted
    const unsigned short* __restrict__ wb1t = (const unsigned short*)(ws + WT_B1);

    // no __syncthreads needed: each wave reads only its own LDS slice
    f32x4 acc = {};
#pragma unroll
    for (int t = 0; t < 8; ++t) {
        const int k = t * 32 + quad * 8;   // storage index base
        uint2 uaw = *(const uint2*)&sm[wave][l16][k];
        uint2 ubw = *(const uint2*)&sm[wave][16 + l16][k];
        float4 wA = *(const float4*)(wd + k);
        float4 wB = *(const float4*)(wd + k + 4);
        float4 bA = *(const float4*)(bb0 + k);
        float4 bB = *(const float4*)(bb0 + k + 4);
        f32x2 a01 = __builtin_amdgcn_cvt_pk_f32_fp8((int)uaw.x, false);
        f32x2 a23 = __builtin_amdgcn_cvt_pk_f32_fp8((int)uaw.x, true);
        f32x2 a45 = __builtin_amdgcn_cvt_pk_f32_fp8((int)uaw.y, false);
        f32x2 a67 = __builtin_amdgcn_cvt_pk_f32_fp8((int)uaw.y, true);
        f32x2 b01 = __builtin_amdgcn_cvt_pk_f32_fp8((int)ubw.x, false);
        f32x2 b23 = __builtin_amdgcn_cvt_pk_f32_fp8((int)ubw.x, true);
        f32x2 b45 = __builtin_amdgcn_cvt_pk_f32_fp8((int)ubw.y, false);
        f32x2 b67 = __builtin_amdgcn_cvt_pk_f32_fp8((int)ubw.y, true);
        union { bf16x8 v; unsigned short s[8]; } af;
        af.s[0] = bbits(silu(a01.x + b01.x + fmaf(d, wA.x, bA.x)));
        af.s[1] = bbits(silu(a01.y + b01.y + fmaf(d, wA.y, bA.y)));
        af.s[2] = bbits(silu(a23.x + b23.x + fmaf(d, wA.z, bA.z)));
        af.s[3] = bbits(silu(a23.y + b23.y + fmaf(d, wA.w, bA.w)));
        af.s[4] = bbits(silu(a45.x + b45.x + fmaf(d, wB.x, bB.x)));
        af.s[5] = bbits(silu(a45.y + b45.y + fmaf(d, wB.y, bB.y)));
        af.s[6] = bbits(silu(a67.x + b67.x + fmaf(d, wB.z, bB.z)));
        af.s[7] = bbits(silu(a67.y + b67.y + fmaf(d, wB.w, bB.w)));
        bf16x8 bfr = *(const bf16x8*)(wb1t + (size_t)l16 * S_DIM + k);
        acc = __builtin_amdgcn_mfma_f32_16x16x32_bf16(af.v, bfr, acc, 0, 0, 0);
    }

    // epilogue: lane col n=l16 (10 valid), rows = e0 + quad*4 + r
    if (l16 < 10) {
        const float bv = ws[WS_BB1 + l16];
#pragma unroll
        for (int r = 0; r < 4; ++r) {
            const int er = e0 + quad * 4 + r;
            if (er < EG_EDGES) {
                float v = acc[r] + bv;
                if (l16 < 5) stout(out, f32o, O_BPRED + (size_t)er * 5 + l16, v);
                else         stout(out, f32o, O_BEPS + (size_t)er * 5 + (l16 - 5), v);
            }
        }
    }
}

extern "C" void kernel_launch(void* const* d_in, const int* in_sizes, int n_in,
                              void* d_out, int out_size, void* d_ws, size_t ws_size,
                              hipStream_t stream) {
    const void* x        = d_in[0];
    const void* t        = d_in[1];
    const void* pos      = d_in[2];
    const int*  eil      = (const int*)d_in[3];
    const int*  eig      = (const int*)d_in[4];
    const int*  batch    = (const int*)d_in[6];
    const void* W_time   = d_in[7];
    const void* b_time   = d_in[8];
    const void* W_atom   = d_in[9];
    const void* b_atom   = d_in[10];
    const void* W_at     = d_in[11];
    const void* b_at     = d_in[12];
    const void* W_shared = d_in[13];
    const void* b_shared = d_in[14];
    const void* W_b0     = d_in[15];
    const void* b_b0     = d_in[16];
    const void* W_b1     = d_in[17];
    const void* b_b1     = d_in[18];
    const void* W_atoms  = d_in[20];
    const void* b_atoms  = d_in[21];
    (void)in_sizes; (void)n_in; (void)out_size;

    const size_t NEED = (size_t)WS_END_FLOATS * sizeof(float);
    if (ws_size < NEED) return;

    float* ws = (float*)d_ws;
    unsigned int* hbuf = (unsigned int*)(ws + WS_H);

    k_prep<<<640, 256, 0, stream>>>(x, t, W_time, b_time, W_atom, b_atom,
                                    W_at, b_at, W_shared, b_shared, W_b0, b_b0,
                                    W_b1, b_b1, W_atoms, b_atoms, ws);
    k_pos<<<G_GRAPHS, 256, 0, stream>>>(pos, batch, ws, d_out);
    k_node<<<N_NODES / 16, 256, 0, stream>>>(batch, ws, hbuf, d_out);
    k_local<<<(EL_EDGES + 255) / 256, 256, 0, stream>>>(eil, ws, d_out);
    k_bonds<<<(EG_EDGES + 63) / 64, 256, 0, stream>>>(eig, ws,
                                                      (const unsigned char*)hbuf, d_out);
}